// Round 3
// baseline (3169.054 us; speedup 1.0000x reference)
//
#include <hip/hip_runtime.h>
#include <hip/hip_bf16.h>

typedef __hip_bfloat16 bf16;

#define B_  8
#define C_  512
#define N_  4096
#define CQ_ 64

// ---------------------------------------------------------------------------
// Kernel 1: out[b, n, o] = sum_c W[o,c] * x[b,c,n] + bias[o]
// x: [B, C, N] f32.  W: [OC, C] f32.  out: [B, N, OC] (f32 or bf16)
// Tiles: 64 n x 64 o, k-tile 16.  256 threads, 4x4 outputs each.
// ---------------------------------------------------------------------------
template <bool BF16OUT>
__global__ __launch_bounds__(256) void qkv_gemm(
    const float* __restrict__ x, const float* __restrict__ Wm,
    const float* __restrict__ bias, void* __restrict__ outp, int OC)
{
    const int b  = blockIdx.z;
    const int n0 = blockIdx.y * 64;
    const int o0 = blockIdx.x * 64;
    const int t  = threadIdx.x;
    const int tx = t & 15, ty = t >> 4;

    __shared__ float xs[16][68];
    __shared__ float ws[16][68];

    float acc[4][4];
#pragma unroll
    for (int i = 0; i < 4; i++)
#pragma unroll
        for (int j = 0; j < 4; j++) acc[i][j] = 0.f;

    const float* xb = x + (size_t)b * C_ * N_;

    for (int c0 = 0; c0 < C_; c0 += 16) {
        // stage x[c0+row][n0 .. n0+63]: one float4 per thread
        {
            int row = t >> 4, col4 = (t & 15) * 4;
            float4 v = *(const float4*)&xb[(size_t)(c0 + row) * N_ + n0 + col4];
            *(float4*)&xs[row][col4] = v;
        }
        // stage W[o0+oo][c0 .. c0+15]: one float4 per thread, transposed into ws[kk][oo]
        {
            int oo = t >> 2, kk4 = (t & 3) * 4;
            float4 v = *(const float4*)&Wm[(size_t)(o0 + oo) * C_ + c0 + kk4];
            ws[kk4 + 0][oo] = v.x;
            ws[kk4 + 1][oo] = v.y;
            ws[kk4 + 2][oo] = v.z;
            ws[kk4 + 3][oo] = v.w;
        }
        __syncthreads();
#pragma unroll
        for (int kk = 0; kk < 16; kk++) {
            float4 a = *(const float4*)&xs[kk][ty * 4];
            float4 w = *(const float4*)&ws[kk][tx * 4];
            float av[4] = {a.x, a.y, a.z, a.w};
            float wv[4] = {w.x, w.y, w.z, w.w};
#pragma unroll
            for (int i = 0; i < 4; i++)
#pragma unroll
                for (int j = 0; j < 4; j++) acc[i][j] += av[i] * wv[j];
        }
        __syncthreads();
    }

    float bv[4];
#pragma unroll
    for (int j = 0; j < 4; j++) bv[j] = bias[o0 + tx * 4 + j];

    if (BF16OUT) {
        bf16* out = (bf16*)outp + (size_t)b * N_ * OC;
#pragma unroll
        for (int i = 0; i < 4; i++) {
            int n = n0 + ty * 4 + i;
            union { bf16 h[4]; uint2 u; } pk;
#pragma unroll
            for (int j = 0; j < 4; j++) pk.h[j] = __float2bfloat16(acc[i][j] + bv[j]);
            *(uint2*)&out[(size_t)n * OC + o0 + tx * 4] = pk.u;
        }
    } else {
        float* out = (float*)outp + (size_t)b * N_ * OC;
#pragma unroll
        for (int i = 0; i < 4; i++) {
            int n = n0 + ty * 4 + i;
            float4 v;
            v.x = acc[i][0] + bv[0]; v.y = acc[i][1] + bv[1];
            v.z = acc[i][2] + bv[2]; v.w = acc[i][3] + bv[3];
            *(float4*)&out[(size_t)n * OC + o0 + tx * 4] = v;
        }
    }
}

// ---------------------------------------------------------------------------
// Kernel 2: per-row softmax stats over energy[i,j] = Q[i].K[j]
// Q,K: [B, N, 64] f32.  Writes M[b,n], L[b,n].
// Block: 64 i-rows.  256 threads (16x16), thread = 4i x 4j of each S tile.
// ---------------------------------------------------------------------------
__global__ __launch_bounds__(256) void attn_stats(
    const float* __restrict__ Q, const float* __restrict__ K,
    float* __restrict__ Mrow, float* __restrict__ Lrow)
{
    const int b  = blockIdx.y;
    const int i0 = blockIdx.x * 64;
    const int t  = threadIdx.x;
    const int tx = t & 15, ty = t >> 4;

    __shared__ float qs[64][68];
    __shared__ float ks[64][68];

    const float* Qb = Q + ((size_t)b * N_ + i0) * CQ_;
#pragma unroll
    for (int r = 0; r < 16; r++) {
        int idx = t + r * 256;
        qs[idx >> 6][idx & 63] = Qb[idx];
    }

    float m[4], l[4];
#pragma unroll
    for (int i = 0; i < 4; i++) { m[i] = -3.0e38f; l[i] = 0.f; }

    for (int jt = 0; jt < 64; jt++) {
        __syncthreads();
        const float* Kb = K + ((size_t)b * N_ + jt * 64) * CQ_;
#pragma unroll
        for (int r = 0; r < 16; r++) {
            int idx = t + r * 256;
            ks[idx >> 6][idx & 63] = Kb[idx];
        }
        __syncthreads();

        float s[4][4];
#pragma unroll
        for (int i = 0; i < 4; i++)
#pragma unroll
            for (int j = 0; j < 4; j++) s[i][j] = 0.f;

        for (int kk = 0; kk < 64; kk += 4) {
            float4 qa[4], kb[4];
#pragma unroll
            for (int i = 0; i < 4; i++) qa[i] = *(const float4*)&qs[ty * 4 + i][kk];
#pragma unroll
            for (int j = 0; j < 4; j++) kb[j] = *(const float4*)&ks[tx * 4 + j][kk];
#pragma unroll
            for (int i = 0; i < 4; i++)
#pragma unroll
                for (int j = 0; j < 4; j++)
                    s[i][j] += qa[i].x * kb[j].x + qa[i].y * kb[j].y +
                               qa[i].z * kb[j].z + qa[i].w * kb[j].w;
        }

#pragma unroll
        for (int i = 0; i < 4; i++) {
            float rm = fmaxf(fmaxf(s[i][0], s[i][1]), fmaxf(s[i][2], s[i][3]));
            rm = fmaxf(rm, __shfl_xor(rm, 1, 16));
            rm = fmaxf(rm, __shfl_xor(rm, 2, 16));
            rm = fmaxf(rm, __shfl_xor(rm, 4, 16));
            rm = fmaxf(rm, __shfl_xor(rm, 8, 16));
            float nm = fmaxf(m[i], rm);
            float se = __expf(s[i][0] - nm) + __expf(s[i][1] - nm) +
                       __expf(s[i][2] - nm) + __expf(s[i][3] - nm);
            se += __shfl_xor(se, 1, 16);
            se += __shfl_xor(se, 2, 16);
            se += __shfl_xor(se, 4, 16);
            se += __shfl_xor(se, 8, 16);
            l[i] = l[i] * __expf(m[i] - nm) + se;
            m[i] = nm;
        }
    }

    if (tx == 0) {
#pragma unroll
        for (int i = 0; i < 4; i++) {
            Mrow[(size_t)b * N_ + i0 + ty * 4 + i] = m[i];
            Lrow[(size_t)b * N_ + i0 + ty * 4 + i] = l[i];
        }
    }
}

// ---------------------------------------------------------------------------
// Kernel 3: out[b,c,n] = gamma * (sum_j exp(Q[i].K[j] - m_i) * V[j,c]) / l_i + x[b,c,n]
// Block: 64 i-rows x all 512 channels.  O[4][32] fp32 regs per thread.
// ---------------------------------------------------------------------------
__global__ __launch_bounds__(256) void attn_out(
    const float* __restrict__ Q, const float* __restrict__ K,
    const bf16* __restrict__ V, const float* __restrict__ Mrow,
    const float* __restrict__ Lrow, const float* __restrict__ x,
    const float* __restrict__ gamma, float* __restrict__ out)
{
    const int b  = blockIdx.y;
    const int i0 = blockIdx.x * 64;
    const int t  = threadIdx.x;
    const int tx = t & 15, ty = t >> 4;

    __shared__ float smem[3 * 64 * 68 + 128];
    float* qs = smem;               // [64][68]
    float* ks = smem + 64 * 68;     // [64][68]
    float* ps = smem + 2 * 64 * 68; // [64][68]  P stored transposed: ps[j][i]
    float* ms = smem + 3 * 64 * 68; // [64]
    float* ls = ms + 64;            // [64]
    float* ostage = smem;           // alias qs+ks: [128][65] = 8320 floats

    const float* Qb = Q + ((size_t)b * N_ + i0) * CQ_;
#pragma unroll
    for (int r = 0; r < 16; r++) {
        int idx = t + r * 256;
        qs[(idx >> 6) * 68 + (idx & 63)] = Qb[idx];
    }
    if (t < 64) {
        ms[t] = Mrow[(size_t)b * N_ + i0 + t];
        ls[t] = Lrow[(size_t)b * N_ + i0 + t];
    }
    __syncthreads();

    const float g = gamma[0];
    float mi[4], sl[4];
#pragma unroll
    for (int i = 0; i < 4; i++) {
        mi[i] = ms[ty * 4 + i];
        sl[i] = g / ls[ty * 4 + i];
    }

    float O[4][32];
#pragma unroll
    for (int i = 0; i < 4; i++)
#pragma unroll
        for (int u = 0; u < 32; u++) O[i][u] = 0.f;

    for (int jt = 0; jt < 64; jt++) {
        const float* Kb = K + ((size_t)b * N_ + jt * 64) * CQ_;
#pragma unroll
        for (int r = 0; r < 16; r++) {
            int idx = t + r * 256;
            ks[(idx >> 6) * 68 + (idx & 63)] = Kb[idx];
        }
        __syncthreads();

        float s[4][4];
#pragma unroll
        for (int i = 0; i < 4; i++)
#pragma unroll
            for (int j = 0; j < 4; j++) s[i][j] = 0.f;

        for (int kk = 0; kk < 64; kk += 4) {
            float4 qa[4], kb[4];
#pragma unroll
            for (int i = 0; i < 4; i++) qa[i] = *(const float4*)&qs[(ty * 4 + i) * 68 + kk];
#pragma unroll
            for (int j = 0; j < 4; j++) kb[j] = *(const float4*)&ks[(tx * 4 + j) * 68 + kk];
#pragma unroll
            for (int i = 0; i < 4; i++)
#pragma unroll
                for (int j = 0; j < 4; j++)
                    s[i][j] += qa[i].x * kb[j].x + qa[i].y * kb[j].y +
                               qa[i].z * kb[j].z + qa[i].w * kb[j].w;
        }
#pragma unroll
        for (int i = 0; i < 4; i++)
#pragma unroll
            for (int j = 0; j < 4; j++)
                ps[(tx * 4 + j) * 68 + ty * 4 + i] = __expf(s[i][j] - mi[i]);
        __syncthreads();

        const bf16* Vb = V + ((size_t)b * N_ + (size_t)jt * 64) * C_;
        for (int j = 0; j < 64; j++) {
            float4 p4 = *(const float4*)&ps[j * 68 + ty * 4];
            float pv[4] = {p4.x, p4.y, p4.z, p4.w};
            const bf16* vr = Vb + (size_t)j * C_;
#pragma unroll
            for (int cc = 0; cc < 4; cc++) {
                uint4 raw = *(const uint4*)(vr + cc * 128 + tx * 8);
                float vv[8];
                vv[0] = __uint_as_float(raw.x << 16);
                vv[1] = __uint_as_float(raw.x & 0xffff0000u);
                vv[2] = __uint_as_float(raw.y << 16);
                vv[3] = __uint_as_float(raw.y & 0xffff0000u);
                vv[4] = __uint_as_float(raw.z << 16);
                vv[5] = __uint_as_float(raw.z & 0xffff0000u);
                vv[6] = __uint_as_float(raw.w << 16);
                vv[7] = __uint_as_float(raw.w & 0xffff0000u);
#pragma unroll
                for (int i = 0; i < 4; i++)
#pragma unroll
                    for (int e = 0; e < 8; e++)
                        O[i][cc * 8 + e] += pv[i] * vv[e];
            }
        }
        __syncthreads();  // protect ps/ks before next iteration's writes
    }

    // scale by gamma / l
#pragma unroll
    for (int i = 0; i < 4; i++)
#pragma unroll
        for (int u = 0; u < 32; u++) O[i][u] *= sl[i];

    // staged transpose -> coalesced f32 stores, fused residual add
    for (int cc = 0; cc < 4; cc++) {
        __syncthreads();
#pragma unroll
        for (int e = 0; e < 8; e++)
#pragma unroll
            for (int i = 0; i < 4; i++)
                ostage[(tx * 8 + e) * 65 + ty * 4 + i] = O[i][cc * 8 + e];
        __syncthreads();
#pragma unroll
        for (int r = 0; r < 32; r++) {
            int cl = (t >> 6) + r * 4;   // 0..127
            int il = t & 63;
            int c = cc * 128 + cl;
            int n = i0 + il;
            size_t gidx = (size_t)b * C_ * N_ + (size_t)c * N_ + n;
            out[gidx] = ostage[cl * 65 + il] + x[gidx];
        }
    }
}

// ---------------------------------------------------------------------------
extern "C" void kernel_launch(void* const* d_in, const int* in_sizes, int n_in,
                              void* d_out, int out_size, void* d_ws, size_t ws_size,
                              hipStream_t stream)
{
    const float* x     = (const float*)d_in[0];
    const float* Wq    = (const float*)d_in[1];
    const float* bq    = (const float*)d_in[2];
    const float* Wk    = (const float*)d_in[3];
    const float* bk    = (const float*)d_in[4];
    const float* Wv    = (const float*)d_in[5];
    const float* bv    = (const float*)d_in[6];
    const float* gamma = (const float*)d_in[7];
    float* out = (float*)d_out;

    dim3 blk(256);

    // Full-footprint layout: Q(8MB f32) K(8MB f32) V(32MB bf16) M(128K) L(128K)
    const size_t szQ = (size_t)B_ * N_ * CQ_ * sizeof(float);   // 8,388,608
    const size_t szV = (size_t)B_ * N_ * C_ * sizeof(bf16);     // 33,554,432
    const size_t szM = (size_t)B_ * N_ * sizeof(float);         // 131,072
    const size_t need_full = 2 * szQ + szV + 2 * szM;           // 50,593,792

    if (ws_size >= need_full) {
        char* ws = (char*)d_ws;
        float* Q  = (float*)ws;
        float* K  = (float*)(ws + szQ);
        bf16*  V  = (bf16*) (ws + 2 * szQ);
        float* Mr = (float*)(ws + 2 * szQ + szV);
        float* Lr = (float*)(ws + 2 * szQ + szV + szM);

        qkv_gemm<false><<<dim3(1, 64, B_), blk, 0, stream>>>(x, Wq, bq, Q, CQ_);
        qkv_gemm<false><<<dim3(1, 64, B_), blk, 0, stream>>>(x, Wk, bk, K, CQ_);
        qkv_gemm<true ><<<dim3(8, 64, B_), blk, 0, stream>>>(x, Wv, bv, V, C_);
        attn_stats<<<dim3(64, B_), blk, 0, stream>>>(Q, K, Mr, Lr);
        attn_out<<<dim3(64, B_), blk, 0, stream>>>(Q, K, V, Mr, Lr, x, gamma, out);
    } else {
        // Per-batch chunked path: Q(1MB) K(1MB) V(4MB) M(16K) L(16K) = 6.33 MB.
        // Stream order serializes reuse of the scratch.
        const size_t qb = (size_t)N_ * CQ_ * sizeof(float);     // 1,048,576
        const size_t vb = (size_t)N_ * C_ * sizeof(bf16);       // 4,194,304
        const size_t mb = (size_t)N_ * sizeof(float);           // 16,384
        char* ws = (char*)d_ws;
        float* Q  = (float*)ws;
        float* K  = (float*)(ws + qb);
        bf16*  V  = (bf16*) (ws + 2 * qb);
        float* Mr = (float*)(ws + 2 * qb + vb);
        float* Lr = (float*)(ws + 2 * qb + vb + mb);

        for (int b = 0; b < B_; b++) {
            const float* xb = x + (size_t)b * C_ * N_;
            float*       ob = out + (size_t)b * C_ * N_;
            qkv_gemm<false><<<dim3(1, 64, 1), blk, 0, stream>>>(xb, Wq, bq, Q, CQ_);
            qkv_gemm<false><<<dim3(1, 64, 1), blk, 0, stream>>>(xb, Wk, bk, K, CQ_);
            qkv_gemm<true ><<<dim3(8, 64, 1), blk, 0, stream>>>(xb, Wv, bv, V, C_);
            attn_stats<<<dim3(64, 1), blk, 0, stream>>>(Q, K, Mr, Lr);
            attn_out<<<dim3(64, 1), blk, 0, stream>>>(Q, K, V, Mr, Lr, xb, gamma, ob);
        }
    }
}

// Round 4
// 696.040 us; speedup vs baseline: 4.5530x; 4.5530x over previous
//
#include <hip/hip_runtime.h>
#include <hip/hip_bf16.h>

typedef __hip_bfloat16 bf16;
typedef __attribute__((ext_vector_type(4))) float f32x4;
typedef __attribute__((ext_vector_type(8))) short bs8;

#define B_  8
#define C_  512
#define N_  4096
#define CQ_ 64

#define MFMA16(a, b, c) __builtin_amdgcn_mfma_f32_16x16x32_bf16(a, b, c, 0, 0, 0)

// ---------------------------------------------------------------------------
// Q/K GEMM: out[b, n, o] = sum_c W[o,c] * x[b,c,n] + bias[o]   (bf16 out, OC=64)
// fp32 VALU compute, tiles 64n x 64o, k-tile 16. 256 threads, 4x4 per thread.
// ---------------------------------------------------------------------------
__global__ __launch_bounds__(256) void qk_gemm(
    const float* __restrict__ x, const float* __restrict__ Wm,
    const float* __restrict__ bias, bf16* __restrict__ outp)
{
    const int b  = blockIdx.z;
    const int n0 = blockIdx.y * 64;
    const int t  = threadIdx.x;
    const int tx = t & 15, ty = t >> 4;

    __shared__ float xs[16][68];
    __shared__ float ws[16][68];

    float acc[4][4];
#pragma unroll
    for (int i = 0; i < 4; i++)
#pragma unroll
        for (int j = 0; j < 4; j++) acc[i][j] = 0.f;

    const float* xb = x + (size_t)b * C_ * N_;

    for (int c0 = 0; c0 < C_; c0 += 16) {
        {
            int row = t >> 4, col4 = (t & 15) * 4;
            float4 v = *(const float4*)&xb[(size_t)(c0 + row) * N_ + n0 + col4];
            *(float4*)&xs[row][col4] = v;
        }
        {
            int oo = t >> 2, kk4 = (t & 3) * 4;
            float4 v = *(const float4*)&Wm[(size_t)oo * C_ + c0 + kk4];
            ws[kk4 + 0][oo] = v.x;
            ws[kk4 + 1][oo] = v.y;
            ws[kk4 + 2][oo] = v.z;
            ws[kk4 + 3][oo] = v.w;
        }
        __syncthreads();
#pragma unroll
        for (int kk = 0; kk < 16; kk++) {
            float4 a = *(const float4*)&xs[kk][ty * 4];
            float4 w = *(const float4*)&ws[kk][tx * 4];
            float av[4] = {a.x, a.y, a.z, a.w};
            float wv[4] = {w.x, w.y, w.z, w.w};
#pragma unroll
            for (int i = 0; i < 4; i++)
#pragma unroll
                for (int j = 0; j < 4; j++) acc[i][j] += av[i] * wv[j];
        }
        __syncthreads();
    }

    float bv[4];
#pragma unroll
    for (int j = 0; j < 4; j++) bv[j] = bias[tx * 4 + j];

    bf16* out = outp + (size_t)b * N_ * CQ_;
#pragma unroll
    for (int i = 0; i < 4; i++) {
        int n = n0 + ty * 4 + i;
        union { bf16 h[4]; uint2 u; } pk;
#pragma unroll
        for (int j = 0; j < 4; j++) pk.h[j] = __float2bfloat16(acc[i][j] + bv[j]);
        *(uint2*)&out[(size_t)n * CQ_ + tx * 4] = pk.u;
    }
}

// ---------------------------------------------------------------------------
// V GEMM, transposed output: out[b, o, n] = sum_c W[o,c] x[b,c,n] + bias[o]
// bf16 out in [B, C, N] (channel-major) for direct MFMA B-frag reads.
// ---------------------------------------------------------------------------
__global__ __launch_bounds__(256) void vt_gemm(
    const float* __restrict__ x, const float* __restrict__ Wm,
    const float* __restrict__ bias, bf16* __restrict__ outp)
{
    const int b  = blockIdx.z;
    const int n0 = blockIdx.y * 64;
    const int o0 = blockIdx.x * 64;
    const int t  = threadIdx.x;
    const int tx = t & 15, ty = t >> 4;

    __shared__ float xs[16][68];
    __shared__ float ws[16][68];
    __shared__ bf16  tstage[64][72];

    float acc[4][4];
#pragma unroll
    for (int i = 0; i < 4; i++)
#pragma unroll
        for (int j = 0; j < 4; j++) acc[i][j] = 0.f;

    const float* xb = x + (size_t)b * C_ * N_;

    for (int c0 = 0; c0 < C_; c0 += 16) {
        {
            int row = t >> 4, col4 = (t & 15) * 4;
            float4 v = *(const float4*)&xb[(size_t)(c0 + row) * N_ + n0 + col4];
            *(float4*)&xs[row][col4] = v;
        }
        {
            int oo = t >> 2, kk4 = (t & 3) * 4;
            float4 v = *(const float4*)&Wm[(size_t)(o0 + oo) * C_ + c0 + kk4];
            ws[kk4 + 0][oo] = v.x;
            ws[kk4 + 1][oo] = v.y;
            ws[kk4 + 2][oo] = v.z;
            ws[kk4 + 3][oo] = v.w;
        }
        __syncthreads();
#pragma unroll
        for (int kk = 0; kk < 16; kk++) {
            float4 a = *(const float4*)&xs[kk][ty * 4];
            float4 w = *(const float4*)&ws[kk][tx * 4];
            float av[4] = {a.x, a.y, a.z, a.w};
            float wv[4] = {w.x, w.y, w.z, w.w};
#pragma unroll
            for (int i = 0; i < 4; i++)
#pragma unroll
                for (int j = 0; j < 4; j++) acc[i][j] += av[i] * wv[j];
        }
        __syncthreads();
    }

    float bv[4];
#pragma unroll
    for (int j = 0; j < 4; j++) bv[j] = bias[o0 + tx * 4 + j];

    // transpose through LDS: tstage[o_local][n_local]
#pragma unroll
    for (int i = 0; i < 4; i++)
#pragma unroll
        for (int j = 0; j < 4; j++)
            tstage[tx * 4 + j][ty * 4 + i] = __float2bfloat16(acc[i][j] + bv[j]);
    __syncthreads();

    {
        int o_l = t >> 2, n16 = (t & 3) * 16;
        uint4 u0 = *(uint4*)&tstage[o_l][n16];
        uint4 u1 = *(uint4*)&tstage[o_l][n16 + 8];
        bf16* dst = outp + ((size_t)b * C_ + o0 + o_l) * N_ + n0 + n16;
        *(uint4*)dst = u0;
        *(uint4*)(dst + 8) = u1;
    }
}

// ---------------------------------------------------------------------------
// Fused attention: for 64 Q-rows, loop 64-j tiles:
//   S = Q.K^T (MFMA), P = exp(S) -> swizzled LDS (bf16),
//   l += P.1 (MFMA vs ones), O += P.V (MFMA, V B-frags direct from global Vt)
// epilogue: out = gamma*O/l + x.
// block: 256 thr = 4 waves; wave w owns c-range [w*128, w*128+128).
// ---------------------------------------------------------------------------
__global__ __launch_bounds__(256, 2) void attn_fused(
    const bf16* __restrict__ Qg, const bf16* __restrict__ Kg,
    const bf16* __restrict__ Vt, const float* __restrict__ x,
    const float* __restrict__ gamma, float* __restrict__ out)
{
    const int b    = blockIdx.x;       // batch on grid.x -> XCD locality (%8)
    const int i0   = blockIdx.y * 64;
    const int t    = threadIdx.x;
    const int wave = t >> 6;
    const int lane = t & 63;
    const int quad = lane >> 4;
    const int l16  = lane & 15;

    // LDS: Q tile [0,8192), P tile [8192,16384). Rows of 128 B, 16B-block
    // xor-swizzle: block' = block ^ (row&7)  -> conflict-free b128 frag reads.
    __shared__ char lds[16384];

    // ---- stage Q tile (64 rows x 64 bf16) ----
    {
        const int r  = t >> 2;
        const int bi = (t & 3) * 2;
        const bf16* src = Qg + ((size_t)b * N_ + i0 + r) * CQ_ + bi * 8;
        uint4 v0 = *(const uint4*)(src);
        uint4 v1 = *(const uint4*)(src + 8);
        *(uint4*)(lds + r * 128 + (((bi    ) ^ (r & 7)) << 4)) = v0;
        *(uint4*)(lds + r * 128 + (((bi + 1) ^ (r & 7)) << 4)) = v1;
    }

    bs8 ones;
#pragma unroll
    for (int e = 0; e < 8; e++) ones[e] = (short)0x3F80;   // bf16 1.0

    f32x4 oacc[4][8];
#pragma unroll
    for (int s = 0; s < 4; s++)
#pragma unroll
        for (int c = 0; c < 8; c++) oacc[s][c] = (f32x4){0.f, 0.f, 0.f, 0.f};
    f32x4 lacc[4];
#pragma unroll
    for (int s = 0; s < 4; s++) lacc[s] = (f32x4){0.f, 0.f, 0.f, 0.f};

    const bf16* Kbase = Kg + ((size_t)b * N_ + wave * 16 + l16) * CQ_ + quad * 8;
    const bf16* Vbase = Vt + ((size_t)b * C_ + wave * 128 + l16) * (size_t)N_ + quad * 8;

    __syncthreads();   // Q staged

    for (int jt = 0; jt < 64; jt++) {
        const int j0 = jt * 64;

        // K B-frags (wave-specific 16 cols) straight from L2
        bs8 kb0 = *(const bs8*)(Kbase + (size_t)j0 * CQ_);
        bs8 kb1 = *(const bs8*)(Kbase + (size_t)j0 * CQ_ + 32);

        // S = Q.K^T for rows i0..i0+63, cols j0+wave*16..+16
        f32x4 sacc[4];
#pragma unroll
        for (int sub = 0; sub < 4; sub++) {
            int r = sub * 16 + l16;
            bs8 qa0 = *(const bs8*)(lds + r * 128 + (((quad    ) ^ (r & 7)) << 4));
            bs8 qa1 = *(const bs8*)(lds + r * 128 + (((quad + 4) ^ (r & 7)) << 4));
            f32x4 z = (f32x4){0.f, 0.f, 0.f, 0.f};
            z = MFMA16(qa0, kb0, z);
            z = MFMA16(qa1, kb1, z);
            sacc[sub] = z;
        }

        __syncthreads();   // previous iteration's P reads complete

        // P = exp(S) -> LDS (C-layout: row=sub*16+quad*4+reg, col=wave*16+l16)
#pragma unroll
        for (int sub = 0; sub < 4; sub++) {
#pragma unroll
            for (int reg = 0; reg < 4; reg++) {
                int row = sub * 16 + quad * 4 + reg;
                int col = wave * 16 + l16;
                bf16 h = __float2bfloat16(__expf(sacc[sub][reg]));
                *(short*)(lds + 8192 + row * 128 +
                          ((((col >> 3) ^ (row & 7)) << 4)) + (col & 7) * 2) = *(short*)&h;
            }
        }
        __syncthreads();   // P ready

        // P A-frags + l accumulation (ones B-frag)
        bs8 pa0[4], pa1[4];
#pragma unroll
        for (int sub = 0; sub < 4; sub++) {
            int r = sub * 16 + l16;
            pa0[sub] = *(const bs8*)(lds + 8192 + r * 128 + (((quad    ) ^ (r & 7)) << 4));
            pa1[sub] = *(const bs8*)(lds + 8192 + r * 128 + (((quad + 4) ^ (r & 7)) << 4));
            lacc[sub] = MFMA16(pa0[sub], ones, lacc[sub]);
            lacc[sub] = MFMA16(pa1[sub], ones, lacc[sub]);
        }

        // O += P.V : V B-frags direct from global (L2), software-prefetched
        const bf16* vj = Vbase + j0;
        bs8 vb0 = *(const bs8*)(vj);
        bs8 vb1 = *(const bs8*)(vj + 32);
#pragma unroll
        for (int ct = 0; ct < 8; ct++) {
            bs8 nv0, nv1;
            if (ct < 7) {
                nv0 = *(const bs8*)(vj + (size_t)(ct + 1) * 16 * N_);
                nv1 = *(const bs8*)(vj + (size_t)(ct + 1) * 16 * N_ + 32);
            }
#pragma unroll
            for (int sub = 0; sub < 4; sub++) {
                oacc[sub][ct] = MFMA16(pa0[sub], vb0, oacc[sub][ct]);
                oacc[sub][ct] = MFMA16(pa1[sub], vb1, oacc[sub][ct]);
            }
            vb0 = nv0; vb1 = nv1;
        }
    }

    // ---- epilogue: out = gamma*O/l + x ----
    const float g = gamma[0];
#pragma unroll
    for (int sub = 0; sub < 4; sub++) {
        float inv0 = g / lacc[sub][0];
        float inv1 = g / lacc[sub][1];
        float inv2 = g / lacc[sub][2];
        float inv3 = g / lacc[sub][3];
#pragma unroll
        for (int ct = 0; ct < 8; ct++) {
            int c = wave * 128 + ct * 16 + l16;
            int n = i0 + sub * 16 + quad * 4;
            size_t idx = ((size_t)b * C_ + c) * N_ + n;
            float4 xv = *(const float4*)(x + idx);
            float4 o;
            o.x = oacc[sub][ct][0] * inv0 + xv.x;
            o.y = oacc[sub][ct][1] * inv1 + xv.y;
            o.z = oacc[sub][ct][2] * inv2 + xv.z;
            o.w = oacc[sub][ct][3] * inv3 + xv.w;
            *(float4*)(out + idx) = o;
        }
    }
}

// ---------------------------------------------------------------------------
extern "C" void kernel_launch(void* const* d_in, const int* in_sizes, int n_in,
                              void* d_out, int out_size, void* d_ws, size_t ws_size,
                              hipStream_t stream)
{
    const float* x     = (const float*)d_in[0];
    const float* Wq    = (const float*)d_in[1];
    const float* bq    = (const float*)d_in[2];
    const float* Wk    = (const float*)d_in[3];
    const float* bk    = (const float*)d_in[4];
    const float* Wv    = (const float*)d_in[5];
    const float* bv    = (const float*)d_in[6];
    const float* gamma = (const float*)d_in[7];
    float* out = (float*)d_out;

    dim3 blk(256);

    const size_t szQ = (size_t)B_ * N_ * CQ_ * sizeof(bf16);   // 4 MB
    const size_t szV = (size_t)B_ * C_ * N_ * sizeof(bf16);    // 32 MB
    const size_t need_full = 2 * szQ + szV;                    // 40 MB

    if (ws_size >= need_full) {
        char* ws = (char*)d_ws;
        bf16* Q  = (bf16*)ws;
        bf16* K  = (bf16*)(ws + szQ);
        bf16* Vt = (bf16*)(ws + 2 * szQ);

        qk_gemm<<<dim3(1, 64, B_), blk, 0, stream>>>(x, Wq, bq, Q);
        qk_gemm<<<dim3(1, 64, B_), blk, 0, stream>>>(x, Wk, bk, K);
        vt_gemm<<<dim3(8, 64, B_), blk, 0, stream>>>(x, Wv, bv, Vt);
        attn_fused<<<dim3(B_, 64), blk, 0, stream>>>(Q, K, Vt, x, gamma, out);
    } else {
        // per-batch chunked: Q 512K + K 512K + Vt 4MB = 5 MB
        const size_t qb = (size_t)N_ * CQ_ * sizeof(bf16);
        const size_t vb2 = (size_t)C_ * N_ * sizeof(bf16);
        char* ws = (char*)d_ws;
        bf16* Q  = (bf16*)ws;
        bf16* K  = (bf16*)(ws + qb);
        bf16* Vt = (bf16*)(ws + 2 * qb);
        (void)vb2;

        for (int b = 0; b < B_; b++) {
            const float* xb = x + (size_t)b * C_ * N_;
            float*       ob = out + (size_t)b * C_ * N_;
            qk_gemm<<<dim3(1, 64, 1), blk, 0, stream>>>(xb, Wq, bq, Q);
            qk_gemm<<<dim3(1, 64, 1), blk, 0, stream>>>(xb, Wk, bk, K);
            vt_gemm<<<dim3(8, 64, 1), blk, 0, stream>>>(xb, Wv, bv, Vt);
            attn_fused<<<dim3(1, 64), blk, 0, stream>>>(Q, K, Vt, xb, gamma, ob);
        }
    }
}

// Round 5
// 630.130 us; speedup vs baseline: 5.0292x; 1.1046x over previous
//
#include <hip/hip_runtime.h>
#include <hip/hip_bf16.h>

typedef __hip_bfloat16 bf16;
typedef __attribute__((ext_vector_type(4))) float f32x4;
typedef __attribute__((ext_vector_type(8))) short bs8;

#define B_  8
#define C_  512
#define N_  4096
#define CQ_ 64

#define MFMA16(a, b, c) __builtin_amdgcn_mfma_f32_16x16x32_bf16(a, b, c, 0, 0, 0)

// ---------------------------------------------------------------------------
// Generic fp32 -> bf16 cast (n divisible by 4)
// ---------------------------------------------------------------------------
__global__ __launch_bounds__(256) void cast_f32_bf16(
    const float* __restrict__ src, bf16* __restrict__ dst, int n4)
{
    int i = blockIdx.x * 256 + threadIdx.x;
    if (i < n4) {
        float4 v = *(const float4*)(src + (size_t)i * 4);
        union { bf16 h[4]; uint2 u; } pk;
        pk.h[0] = __float2bfloat16(v.x);
        pk.h[1] = __float2bfloat16(v.y);
        pk.h[2] = __float2bfloat16(v.z);
        pk.h[3] = __float2bfloat16(v.w);
        *(uint2*)(dst + (size_t)i * 4) = pk.u;
    }
}

// ---------------------------------------------------------------------------
// x [B][C][N] fp32 -> xT [B][N][C] bf16  (64c x 64n tiles via LDS)
// ---------------------------------------------------------------------------
__global__ __launch_bounds__(256) void cast_transpose(
    const float* __restrict__ x, bf16* __restrict__ xT)
{
    const int b = blockIdx.z, c0 = blockIdx.y * 64, n0 = blockIdx.x * 64;
    const int t = threadIdx.x;
    __shared__ bf16 tile[64][72];   // [n][c]

    const float* xb = x + ((size_t)b * C_ + c0) * N_ + n0;
    const int cr = t >> 4;
    const int nc4 = (t & 15) * 4;
#pragma unroll
    for (int r = 0; r < 4; r++) {
        int c = cr + r * 16;
        float4 v = *(const float4*)&xb[(size_t)c * N_ + nc4];
        tile[nc4 + 0][c] = __float2bfloat16(v.x);
        tile[nc4 + 1][c] = __float2bfloat16(v.y);
        tile[nc4 + 2][c] = __float2bfloat16(v.z);
        tile[nc4 + 3][c] = __float2bfloat16(v.w);
    }
    __syncthreads();

    bf16* dst = xT + ((size_t)b * N_ + n0) * C_ + c0;
#pragma unroll
    for (int rep = 0; rep < 2; rep++) {
        int idx = t + rep * 256;
        int row = idx >> 3, seg = idx & 7;
        *(uint4*)&dst[(size_t)row * C_ + seg * 8] = *(uint4*)&tile[row][seg * 8];
    }
}

// ---------------------------------------------------------------------------
// MFMA projection GEMM: D[o][n] = sum_c W[o][c] * xT[n][c] (+bias[o])
// MODE 0: out[n][64] bf16 (Q/K, o0==0).  MODE 1: out[o][N] bf16 (Vt).
// Block: 64o x 64n, 4 waves (wave owns 16 o-rows), K-loop c step 32.
// ---------------------------------------------------------------------------
template <int MODE>
__global__ __launch_bounds__(256, 4) void mfma_gemm(
    const bf16* __restrict__ xT, const bf16* __restrict__ Wb,
    const float* __restrict__ bias, bf16* __restrict__ out)
{
    const int b = blockIdx.z, n0 = blockIdx.x * 64, o0 = blockIdx.y * 64;
    const int t = threadIdx.x;
    const int wave = t >> 6, lane = t & 63, quad = lane >> 4, l16 = lane & 15;
    __shared__ bf16 st[64][72];

    const bf16* Arow = Wb + (size_t)(o0 + wave * 16 + l16) * C_ + quad * 8;
    const bf16* Brow = xT + ((size_t)b * N_ + n0 + l16) * C_ + quad * 8;

    f32x4 acc[4];
#pragma unroll
    for (int nc = 0; nc < 4; nc++) acc[nc] = (f32x4){0.f, 0.f, 0.f, 0.f};

    bs8 a_cur = *(const bs8*)Arow;
    bs8 b_cur[4];
#pragma unroll
    for (int nc = 0; nc < 4; nc++)
        b_cur[nc] = *(const bs8*)(Brow + (size_t)nc * 16 * C_);

#pragma unroll
    for (int c0 = 0; c0 < C_; c0 += 32) {
        bs8 a_nxt;
        bs8 b_nxt[4];
        if (c0 + 32 < C_) {
            a_nxt = *(const bs8*)(Arow + c0 + 32);
#pragma unroll
            for (int nc = 0; nc < 4; nc++)
                b_nxt[nc] = *(const bs8*)(Brow + (size_t)nc * 16 * C_ + c0 + 32);
        }
#pragma unroll
        for (int nc = 0; nc < 4; nc++)
            acc[nc] = MFMA16(a_cur, b_cur[nc], acc[nc]);
        a_cur = a_nxt;
#pragma unroll
        for (int nc = 0; nc < 4; nc++) b_cur[nc] = b_nxt[nc];
    }

    float bias_r[4];
#pragma unroll
    for (int r = 0; r < 4; r++)
        bias_r[r] = bias[o0 + wave * 16 + quad * 4 + r];

#pragma unroll
    for (int nc = 0; nc < 4; nc++)
#pragma unroll
        for (int r = 0; r < 4; r++) {
            bf16 hv = __float2bfloat16(acc[nc][r] + bias_r[r]);
            if (MODE == 0)
                st[nc * 16 + l16][wave * 16 + quad * 4 + r] = hv;
            else
                st[wave * 16 + quad * 4 + r][nc * 16 + l16] = hv;
        }
    __syncthreads();

#pragma unroll
    for (int rep = 0; rep < 2; rep++) {
        int idx = t + rep * 256;
        int row = idx >> 3, seg = idx & 7;
        uint4 v = *(uint4*)&st[row][seg * 8];
        if (MODE == 0)
            *(uint4*)&out[((size_t)b * N_ + n0 + row) * CQ_ + seg * 8] = v;
        else
            *(uint4*)&out[((size_t)b * C_ + o0 + row) * N_ + n0 + seg * 8] = v;
    }
}

// ---------------------------------------------------------------------------
// Fused attention, software-pipelined:
//  per 64-j tile: [issue V ct0-3 + next K] -> S (MFMA) -> P=exp(S) -> LDS
//  (double-buffered, ONE barrier) -> l += P.1 -> O += P.V (circular depth-4
//  V prefetch).  Epilogue: out = gamma*O/l + x.
// ---------------------------------------------------------------------------
__global__ __launch_bounds__(256, 1) void attn_fused(
    const bf16* __restrict__ Qg, const bf16* __restrict__ Kg,
    const bf16* __restrict__ Vt, const float* __restrict__ x,
    const float* __restrict__ gamma, float* __restrict__ out)
{
    const int b    = blockIdx.x;
    const int i0   = blockIdx.y * 64;
    const int t    = threadIdx.x;
    const int wave = t >> 6;
    const int lane = t & 63;
    const int quad = lane >> 4;
    const int l16  = lane & 15;

    // LDS: Q [0,8K), P0 [8K,16K), P1 [16K,24K). 128B rows, 16B-block xor swizzle.
    __shared__ char lds[24576];

    {   // stage Q tile (64 x 64 bf16)
        const int r  = t >> 2;
        const int bi = (t & 3) * 2;
        const bf16* src = Qg + ((size_t)b * N_ + i0 + r) * CQ_ + bi * 8;
        uint4 v0 = *(const uint4*)(src);
        uint4 v1 = *(const uint4*)(src + 8);
        *(uint4*)(lds + r * 128 + (((bi    ) ^ (r & 7)) << 4)) = v0;
        *(uint4*)(lds + r * 128 + (((bi + 1) ^ (r & 7)) << 4)) = v1;
    }

    bs8 ones;
#pragma unroll
    for (int e = 0; e < 8; e++) ones[e] = (short)0x3F80;

    f32x4 oacc[4][8];
#pragma unroll
    for (int s = 0; s < 4; s++)
#pragma unroll
        for (int c = 0; c < 8; c++) oacc[s][c] = (f32x4){0.f, 0.f, 0.f, 0.f};
    f32x4 lacc[4];
#pragma unroll
    for (int s = 0; s < 4; s++) lacc[s] = (f32x4){0.f, 0.f, 0.f, 0.f};

    const bf16* Kbase = Kg + ((size_t)b * N_ + wave * 16 + l16) * CQ_ + quad * 8;
    const bf16* Vbase = Vt + ((size_t)b * C_ + wave * 128 + l16) * (size_t)N_ + quad * 8;

    bs8 kb0 = *(const bs8*)(Kbase);
    bs8 kb1 = *(const bs8*)(Kbase + 32);

    __syncthreads();   // Q staged

    for (int jt = 0; jt < 64; jt++) {
        const int j0 = jt * 64;
        const bf16* vj = Vbase + j0;

        // V prefetch ct0..3 (independent of P/S -> overlaps S+exp+LDS phase)
        bs8 vb[4][2];
#pragma unroll
        for (int p = 0; p < 4; p++) {
            vb[p][0] = *(const bs8*)(vj + (size_t)p * 16 * N_);
            vb[p][1] = *(const bs8*)(vj + (size_t)p * 16 * N_ + 32);
        }
        // next-tile K prefetch
        bs8 nk0, nk1;
        if (jt < 63) {
            nk0 = *(const bs8*)(Kbase + (size_t)(j0 + 64) * CQ_);
            nk1 = *(const bs8*)(Kbase + (size_t)(j0 + 64) * CQ_ + 32);
        }

        // S = Q.K^T  (rows i0..i0+63, cols j0+wave*16..+16)
        f32x4 sacc[4];
#pragma unroll
        for (int sub = 0; sub < 4; sub++) {
            int r = sub * 16 + l16;
            bs8 qa0 = *(const bs8*)(lds + r * 128 + (((quad    ) ^ (r & 7)) << 4));
            bs8 qa1 = *(const bs8*)(lds + r * 128 + (((quad + 4) ^ (r & 7)) << 4));
            f32x4 z = (f32x4){0.f, 0.f, 0.f, 0.f};
            z = MFMA16(qa0, kb0, z);
            z = MFMA16(qa1, kb1, z);
            sacc[sub] = z;
        }

        // P = exp(S) -> double-buffered LDS (no pre-write barrier needed)
        char* pbuf = lds + 8192 + (jt & 1) * 8192;
#pragma unroll
        for (int sub = 0; sub < 4; sub++) {
#pragma unroll
            for (int reg = 0; reg < 4; reg++) {
                int row = sub * 16 + quad * 4 + reg;
                int col = wave * 16 + l16;
                bf16 h = __float2bfloat16(__expf(sacc[sub][reg]));
                *(short*)(pbuf + row * 128 +
                          ((((col >> 3) ^ (row & 7)) << 4)) + (col & 7) * 2) = *(short*)&h;
            }
        }
        __syncthreads();   // P ready (single barrier per jt)

        // P A-frags + l accumulation
        bs8 pa0[4], pa1[4];
#pragma unroll
        for (int sub = 0; sub < 4; sub++) {
            int r = sub * 16 + l16;
            pa0[sub] = *(const bs8*)(pbuf + r * 128 + (((quad    ) ^ (r & 7)) << 4));
            pa1[sub] = *(const bs8*)(pbuf + r * 128 + (((quad + 4) ^ (r & 7)) << 4));
            lacc[sub] = MFMA16(pa0[sub], ones, lacc[sub]);
            lacc[sub] = MFMA16(pa1[sub], ones, lacc[sub]);
        }

        // O += P.V with circular depth-4 register prefetch
#pragma unroll
        for (int ct = 0; ct < 8; ct++) {
            bs8 v0 = vb[ct & 3][0], v1 = vb[ct & 3][1];
            if (ct < 4) {
                vb[ct & 3][0] = *(const bs8*)(vj + (size_t)(ct + 4) * 16 * N_);
                vb[ct & 3][1] = *(const bs8*)(vj + (size_t)(ct + 4) * 16 * N_ + 32);
            }
#pragma unroll
            for (int sub = 0; sub < 4; sub++) {
                oacc[sub][ct] = MFMA16(pa0[sub], v0, oacc[sub][ct]);
                oacc[sub][ct] = MFMA16(pa1[sub], v1, oacc[sub][ct]);
            }
        }

        kb0 = nk0; kb1 = nk1;
    }

    // ---- epilogue: out = gamma*O/l + x ----
    const float g = gamma[0];
#pragma unroll
    for (int sub = 0; sub < 4; sub++) {
        float inv0 = g / lacc[sub][0];
        float inv1 = g / lacc[sub][1];
        float inv2 = g / lacc[sub][2];
        float inv3 = g / lacc[sub][3];
#pragma unroll
        for (int ct = 0; ct < 8; ct++) {
            int c = wave * 128 + ct * 16 + l16;
            int n = i0 + sub * 16 + quad * 4;
            size_t idx = ((size_t)b * C_ + c) * N_ + n;
            float4 xv = *(const float4*)(x + idx);
            float4 o;
            o.x = oacc[sub][ct][0] * inv0 + xv.x;
            o.y = oacc[sub][ct][1] * inv1 + xv.y;
            o.z = oacc[sub][ct][2] * inv2 + xv.z;
            o.w = oacc[sub][ct][3] * inv3 + xv.w;
            *(float4*)(out + idx) = o;
        }
    }
}

// ---------------------------------------------------------------------------
extern "C" void kernel_launch(void* const* d_in, const int* in_sizes, int n_in,
                              void* d_out, int out_size, void* d_ws, size_t ws_size,
                              hipStream_t stream)
{
    const float* x     = (const float*)d_in[0];
    const float* Wq    = (const float*)d_in[1];
    const float* bq    = (const float*)d_in[2];
    const float* Wk    = (const float*)d_in[3];
    const float* bk    = (const float*)d_in[4];
    const float* Wv    = (const float*)d_in[5];
    const float* bv    = (const float*)d_in[6];
    const float* gamma = (const float*)d_in[7];
    float* out = (float*)d_out;

    dim3 blk(256);

    const size_t szXT = (size_t)B_ * N_ * C_ * sizeof(bf16);   // 33,554,432
    const size_t szQ  = (size_t)B_ * N_ * CQ_ * sizeof(bf16);  //  4,194,304
    const size_t szVt = szXT;                                  // 33,554,432
    const size_t szWq = (size_t)CQ_ * C_ * sizeof(bf16);       //     65,536
    const size_t szWv = (size_t)C_ * C_ * sizeof(bf16);        //    524,288
    const size_t need_full = szXT + 2 * szQ + szVt + 2 * szWq + szWv; // ~72.6 MB

    if (ws_size >= need_full) {
        char* ws = (char*)d_ws;
        bf16* xT  = (bf16*)ws;
        bf16* Q   = (bf16*)(ws + szXT);
        bf16* K   = (bf16*)(ws + szXT + szQ);
        bf16* Vt  = (bf16*)(ws + szXT + 2 * szQ);
        bf16* Wqb = (bf16*)(ws + szXT + 2 * szQ + szVt);
        bf16* Wkb = (bf16*)((char*)Wqb + szWq);
        bf16* Wvb = (bf16*)((char*)Wkb + szWq);

        cast_f32_bf16<<<dim3(32), blk, 0, stream>>>(Wq, Wqb, 8192);
        cast_f32_bf16<<<dim3(32), blk, 0, stream>>>(Wk, Wkb, 8192);
        cast_f32_bf16<<<dim3(256), blk, 0, stream>>>(Wv, Wvb, 65536);
        cast_transpose<<<dim3(64, 8, B_), blk, 0, stream>>>(x, xT);

        mfma_gemm<0><<<dim3(64, 1, B_), blk, 0, stream>>>(xT, Wqb, bq, Q);
        mfma_gemm<0><<<dim3(64, 1, B_), blk, 0, stream>>>(xT, Wkb, bk, K);
        mfma_gemm<1><<<dim3(64, 8, B_), blk, 0, stream>>>(xT, Wvb, bv, Vt);

        attn_fused<<<dim3(B_, 64), blk, 0, stream>>>(Q, K, Vt, x, gamma, out);
    } else {
        // Per-batch chunked: W bf16 (0.66 MB) + xT_b (4.19) + Q_b/K_b (0.5+0.5)
        // + Vt_b (4.19) ~= 10.1 MB.
        const size_t xtb = (size_t)N_ * C_ * sizeof(bf16);
        const size_t qb  = (size_t)N_ * CQ_ * sizeof(bf16);
        char* ws = (char*)d_ws;
        bf16* Wqb = (bf16*)ws;
        bf16* Wkb = (bf16*)(ws + szWq);
        bf16* Wvb = (bf16*)(ws + 2 * szWq);
        bf16* xT  = (bf16*)(ws + 2 * szWq + szWv);
        bf16* Q   = (bf16*)((char*)xT + xtb);
        bf16* K   = (bf16*)((char*)Q + qb);
        bf16* Vt  = (bf16*)((char*)K + qb);

        cast_f32_bf16<<<dim3(32), blk, 0, stream>>>(Wq, Wqb, 8192);
        cast_f32_bf16<<<dim3(32), blk, 0, stream>>>(Wk, Wkb, 8192);
        cast_f32_bf16<<<dim3(256), blk, 0, stream>>>(Wv, Wvb, 65536);

        for (int b = 0; b < B_; b++) {
            const float* xb = x + (size_t)b * C_ * N_;
            float*       ob = out + (size_t)b * C_ * N_;
            cast_transpose<<<dim3(64, 8, 1), blk, 0, stream>>>(xb, xT);
            mfma_gemm<0><<<dim3(64, 1, 1), blk, 0, stream>>>(xT, Wqb, bq, Q);
            mfma_gemm<0><<<dim3(64, 1, 1), blk, 0, stream>>>(xT, Wkb, bk, K);
            mfma_gemm<1><<<dim3(64, 8, 1), blk, 0, stream>>>(xT, Wvb, bv, Vt);
            attn_fused<<<dim3(1, 64), blk, 0, stream>>>(Q, K, Vt, xb, gamma, ob);
        }
    }
}